// Round 12
// baseline (314.171 us; speedup 1.0000x reference)
//
#include <hip/hip_runtime.h>
#include <hip/hip_bf16.h>
#include <stdint.h>

// Problem constants (from reference)
#define N1 8
#define N2 8
#define PP 1024
#define DD 768
#define PH 32
#define PW 32
#define OH 512
#define OW 512

#define NKT 12   // 768 / 64 K-tiles (BK=64 i8 elements = 64-B rows)

typedef int i32x4 __attribute__((ext_vector_type(4)));

// ---------------- K1: row L2-normalize f32 -> i8 (q = round(127*x/||x||)) --
// Verified R7/R8/R9: final absmax 3.9e-3 vs threshold 1.35e-2.
__global__ __launch_bounds__(256) void nrm_kernel(
    const float* __restrict__ inA, const float* __restrict__ inB,
    char* __restrict__ outA, char* __restrict__ outB) {
  int row = blockIdx.x;
  const float* src;
  char* dst;
  if (row < N1 * PP) {
    src = inA + (size_t)row * DD;
    dst = outA + (size_t)row * DD;
  } else {
    row -= N1 * PP;
    src = inB + (size_t)row * DD;
    dst = outB + (size_t)row * DD;
  }
  const int t = threadIdx.x;
  const float v0 = src[t], v1 = src[t + 256], v2 = src[t + 512];
  float s = v0 * v0 + v1 * v1 + v2 * v2;
#pragma unroll
  for (int m = 32; m; m >>= 1) s += __shfl_xor(s, m, 64);
  __shared__ float red[4];
  const int wave = t >> 6, lane = t & 63;
  if (lane == 0) red[wave] = s;
  __syncthreads();
  const float inv = 127.0f / sqrtf(red[0] + red[1] + red[2] + red[3]);
  dst[t]       = (char)__float2int_rn(v0 * inv);
  dst[t + 256] = (char)__float2int_rn(v1 * inv);
  dst[t + 512] = (char)__float2int_rn(v2 * inv);
}

__device__ __forceinline__ void gll16(const char* src, char* dst) {
  __builtin_amdgcn_global_load_lds(
      (const __attribute__((address_space(1))) void*)src,
      (__attribute__((address_space(3))) void*)dst, 16, 0, 0);
}

// -------- K2: i8 gram row-max GEMM, 256x256, BK=64, 2-slot dbuf, 2 blk/CU --
// R11: single change vs R8 = LDS 128 KiB (4-slot) -> 64 KiB (2-slot dbuf) +
// __launch_bounds__(512,4), so TWO independent blocks are resident per CU
// (16 waves). Tests the "chip-wide read/MFMA phase alternation" model of the
// 1.65x gap: independent blocks drift, so one block's LDS-read burst overlaps
// the other's MFMA burst (m114 co-scheduling mechanism). R10's 32x32 shape
// is reverted (it reintroduced bank conflicts, 4.7e6, and cost +57%).
// 8 waves (2M x 4N), per-wave C = 128x64, acc[8][4] i32x4 (R8-verified).
// LDS: 2 slots x {A0,A1,B0,B1} x [128 rows][64 B] = 64 KiB.
// Per iter k: stage kt k+1 (4 gll16, slot (k+1)&1; its readers drained
// before iter k-1's closing barrier) -> 12 ds_read_b128 -> 32 MFMA
// (compiler-graduated lgkmcnt) -> vmcnt(0) -> ONE barrier. No setprio (m190).
// Swizzle (R7/R8-verified, 0 conflicts): LDS byte y of an 8-KB half holds
// global byte S(y) = y ^ (((y>>7)&7)<<4); read of (row, col=lk*16):
// (row*64 + lk*16) ^ (((lr>>1)&7)<<4) (lane-constant XOR).
__global__ __launch_bounds__(512, 4) void grami8_kernel(
    const char* __restrict__ fq, const char* __restrict__ gq,
    int* __restrict__ rowmaxI) {
  __shared__ __align__(16) char lds[2][4][8192];  // [slot][A0,A1,B0,B1][.]

  // XCD swizzle: 1024 wgs, 128 contiguous per XCD (bijective, 1024%8==0).
  const int bid = blockIdx.x;
  const int wg = (bid & 7) * 128 + (bid >> 3);
  const int pair = wg >> 4;                 // 0..63
  const int tile = wg & 15;
  const int fn = pair >> 3, gm = pair & 7;
  const int mt = tile >> 2, nt = tile & 3;  // 4x4 tiles of 256x256
  const int brow = mt * 256, bcol = nt * 256;

  const int t = threadIdx.x;
  const int lane = t & 63, wave = t >> 6;
  const int lr = lane & 15, lk = lane >> 4;
  const int wr = wave >> 2, wc = wave & 3;  // 2M x 4N, per-wave 128x64

  const char* rowA = fq + ((size_t)fn * PP + brow) * DD;
  const char* rowB = gq + ((size_t)gm * PP + bcol) * DD;

  // Staging source mapping (R7/R8-verified): chunk t of an 8-KB half holds
  // global bytes S(t*16): x = t*16 ^ (((t>>3)&7)<<4); srow = x>>6; scol=x&63.
  const int xs = (t * 16) ^ (((t >> 3) & 7) << 4);
  const int srow = xs >> 6;          // 0..127 local row
  const int scol = xs & 63;          // 16-aligned byte col

  // Fragment read byte offsets within a half (R7/R8-verified).
  const int swzv = ((lr >> 1) & 7) << 4;
  const int abase = (lr * 64 + lk * 16) ^ swzv;                      // + m*1024
  const int bbase = (wc & 1) * 4096 + ((lr * 64 + lk * 16) ^ swzv);  // + n*1024

#define STAGE(rowPtr, h, kt, slotptr)                                     \
  gll16(rowPtr + (size_t)((h) * 128 + srow) * DD + (kt) * 64 + scol,      \
        (slotptr) + t * 16)

  i32x4 acc[8][4];
#pragma unroll
  for (int i = 0; i < 8; ++i)
#pragma unroll
    for (int j = 0; j < 4; ++j) acc[i][j] = (i32x4){0, 0, 0, 0};

  // Prologue: stage kt 0 into slot 0.
  STAGE(rowB, 0, 0, &lds[0][2][0]);
  STAGE(rowB, 1, 0, &lds[0][3][0]);
  STAGE(rowA, 0, 0, &lds[0][0][0]);
  STAGE(rowA, 1, 0, &lds[0][1][0]);
  asm volatile("s_waitcnt vmcnt(0)" ::: "memory");
  __builtin_amdgcn_s_barrier();
  asm volatile("" ::: "memory");

#pragma unroll 1
  for (int k = 0; k < NKT; ++k) {
    const char* Ab = &lds[k & 1][wr][0];
    const char* Bb = &lds[k & 1][2 + (wc >> 1)][0];

    // Stage kt k+1 into the other slot (its readers drained before the
    // iter-(k-1) closing barrier; writes land under this iter's MFMA).
    if (k + 1 < NKT) {
      const int ns = (k + 1) & 1;
      STAGE(rowB, 0, k + 1, &lds[ns][2][0]);
      STAGE(rowB, 1, k + 1, &lds[ns][3][0]);
      STAGE(rowA, 0, k + 1, &lds[ns][0][0]);
      STAGE(rowA, 1, k + 1, &lds[ns][1][0]);
    }

    // 12 ds_read_b128; compiler inserts fine-grained lgkmcnt before each
    // dependent MFMA (no explicit drain).
    i32x4 a[8], b[4];
#pragma unroll
    for (int m = 0; m < 8; ++m)
      a[m] = *(const i32x4*)(Ab + abase + m * 1024);
#pragma unroll
    for (int n = 0; n < 4; ++n)
      b[n] = *(const i32x4*)(Bb + bbase + n * 1024);

#pragma unroll
    for (int m = 0; m < 8; ++m)
#pragma unroll
      for (int n = 0; n < 4; ++n)
        acc[m][n] = __builtin_amdgcn_mfma_i32_16x16x64_i8(a[m], b[n],
                                                          acc[m][n], 0, 0, 0);

    // Slot k+1 must be resident before next iter's reads.
    asm volatile("s_waitcnt vmcnt(0)" ::: "memory");
    __builtin_amdgcn_s_barrier();
    asm volatile("" ::: "memory");
  }

  // Row-max epilogue (i32 dot is monotone with gram). C/D layout: col = lr,
  // row = lk*4 + reg (shape-determined, dtype-independent).
  int* rm = rowmaxI + (size_t)(fn * 8 + gm) * PP;
#pragma unroll
  for (int m = 0; m < 8; ++m) {
#pragma unroll
    for (int r = 0; r < 4; ++r) {
      int vv = max(max(acc[m][0][r], acc[m][1][r]),
                   max(acc[m][2][r], acc[m][3][r]));
      vv = max(vv, __shfl_xor(vv, 1, 64));
      vv = max(vv, __shfl_xor(vv, 2, 64));
      vv = max(vv, __shfl_xor(vv, 4, 64));
      vv = max(vv, __shfl_xor(vv, 8, 64));
      if (lr == 0) {
        const int row = brow + wr * 128 + m * 16 + lk * 4 + r;
        atomicMax(&rm[row], vv);
      }
    }
  }
#undef STAGE
}

// ---------------- K3: rowmax(i32) -> dist -> scores + sp ----------------
__global__ __launch_bounds__(256) void finalize_kernel(
    const int* __restrict__ rowmaxI, float* __restrict__ sp,
    float* __restrict__ scores) {
  const int n = blockIdx.x, t = threadIdx.x;
  const int lane = t & 63, wave = t >> 6;
  __shared__ float red[4];
  __shared__ float maxd[N2];
  float spacc[4] = {0.f, 0.f, 0.f, 0.f};
  for (int m = 0; m < N2; ++m) {
    float lmax = -1e30f;
#pragma unroll
    for (int i = 0; i < 4; ++i) {
      const int p = t + i * 256;
      const float g = (float)rowmaxI[(size_t)(n * N2 + m) * PP + p] *
                      (1.0f / 16129.0f);  // 127^2
      const float d = 0.5f * sqrtf(fmaxf(0.f, 2.f - 2.f * g));
      spacc[i] += d;
      lmax = fmaxf(lmax, d);
    }
#pragma unroll
    for (int msk = 32; msk; msk >>= 1) lmax = fmaxf(lmax, __shfl_xor(lmax, msk, 64));
    if (lane == 0) red[wave] = lmax;
    __syncthreads();
    if (t == 0) maxd[m] = fmaxf(fmaxf(red[0], red[1]), fmaxf(red[2], red[3]));
    __syncthreads();
  }
  if (t == 0) {
    float s = 0.f;
    for (int m = 0; m < N2; ++m) s += maxd[m];
    scores[n] = s * (1.0f / N2);
  }
#pragma unroll
  for (int i = 0; i < 4; ++i)
    sp[(size_t)n * PP + t + i * 256] = spacc[i] * (1.0f / N2);
}

// ---------------- K4: bilinear resize 32x32 -> 512x512 ----------------
__global__ __launch_bounds__(256) void resize_kernel(
    const float* __restrict__ sp, float* __restrict__ out) {
  const int idx = blockIdx.x * 256 + threadIdx.x;
  const int ox = idx & (OW - 1);
  const int oy = (idx >> 9) & (OH - 1);
  const int n = idx >> 18;
  const float sy = (oy + 0.5f) * ((float)PH / OH) - 0.5f;
  const float sx = (ox + 0.5f) * ((float)PW / OW) - 0.5f;
  const float y0f = floorf(sy), x0f = floorf(sx);
  const float wy = sy - y0f, wx = sx - x0f;
  int y0 = (int)y0f, x0 = (int)x0f;
  int y1 = y0 + 1, x1 = x0 + 1;
  y0 = min(max(y0, 0), PH - 1);
  y1 = min(max(y1, 0), PH - 1);
  x0 = min(max(x0, 0), PW - 1);
  x1 = min(max(x1, 0), PW - 1);
  const float* s = sp + (size_t)n * PP;
  const float v00 = s[y0 * PW + x0], v01 = s[y0 * PW + x1];
  const float v10 = s[y1 * PW + x0], v11 = s[y1 * PW + x1];
  const float top = v00 * (1.f - wx) + v01 * wx;
  const float bot = v10 * (1.f - wx) + v11 * wx;
  out[idx] = top * (1.f - wy) + bot * wy;
}

extern "C" void kernel_launch(void* const* d_in, const int* in_sizes, int n_in,
                              void* d_out, int out_size, void* d_ws, size_t ws_size,
                              hipStream_t stream) {
  const float* feats = (const float*)d_in[0];
  const float* nfeats = (const float*)d_in[1];
  float* out = (float*)d_out;

  char* ws = (char*)d_ws;
  const size_t FQ_BYTES = (size_t)N1 * PP * DD;  // 6,291,456
  char* fq = ws;
  char* gq = ws + FQ_BYTES;
  int* rowmaxI = (int*)(ws + 2 * FQ_BYTES);
  float* sp = (float*)(ws + 2 * FQ_BYTES + (size_t)N1 * N2 * PP * 4);

  // rowmax sentinel: 0x80808080 = -2139062144 < -768*127^2 (min possible dot)
  hipMemsetAsync(rowmaxI, 0x80, (size_t)N1 * N2 * PP * 4, stream);

  nrm_kernel<<<(N1 + N2) * PP, 256, 0, stream>>>(feats, nfeats, fq, gq);

  grami8_kernel<<<1024, 512, 0, stream>>>(fq, gq, rowmaxI);

  finalize_kernel<<<N1, 256, 0, stream>>>(rowmaxI, sp, out);
  resize_kernel<<<(N1 * OH * OW) / 256, 256, 0, stream>>>(sp, out + 8);
}

// Round 13
// 115.910 us; speedup vs baseline: 2.7105x; 2.7105x over previous
//
#include <hip/hip_runtime.h>
#include <hip/hip_bf16.h>
#include <stdint.h>

// Problem constants (from reference)
#define N1 8
#define N2 8
#define PP 1024
#define DD 768
#define PH 32
#define PW 32
#define OH 512
#define OW 512

#define NKT 12   // 768 / 64 K-tiles (BK=64 i8 elements = 64-B rows)

typedef int i32x4 __attribute__((ext_vector_type(4)));

// ---------------- K1: row L2-normalize f32 -> i8 (q = round(127*x/||x||)) --
// Verified R7/R8/R9: final absmax 3.9e-3 vs threshold 1.35e-2.
__global__ __launch_bounds__(256) void nrm_kernel(
    const float* __restrict__ inA, const float* __restrict__ inB,
    char* __restrict__ outA, char* __restrict__ outB) {
  int row = blockIdx.x;
  const float* src;
  char* dst;
  if (row < N1 * PP) {
    src = inA + (size_t)row * DD;
    dst = outA + (size_t)row * DD;
  } else {
    row -= N1 * PP;
    src = inB + (size_t)row * DD;
    dst = outB + (size_t)row * DD;
  }
  const int t = threadIdx.x;
  const float v0 = src[t], v1 = src[t + 256], v2 = src[t + 512];
  float s = v0 * v0 + v1 * v1 + v2 * v2;
#pragma unroll
  for (int m = 32; m; m >>= 1) s += __shfl_xor(s, m, 64);
  __shared__ float red[4];
  const int wave = t >> 6, lane = t & 63;
  if (lane == 0) red[wave] = s;
  __syncthreads();
  const float inv = 127.0f / sqrtf(red[0] + red[1] + red[2] + red[3]);
  dst[t]       = (char)__float2int_rn(v0 * inv);
  dst[t + 256] = (char)__float2int_rn(v1 * inv);
  dst[t + 512] = (char)__float2int_rn(v2 * inv);
}

__device__ __forceinline__ void gll16(const char* src, char* dst) {
  __builtin_amdgcn_global_load_lds(
      (const __attribute__((address_space(1))) void*)src,
      (__attribute__((address_space(3))) void*)dst, 16, 0, 0);
}

// -------- K2: i8 gram row-max, 128x128 tile, BK=64, 2-slot dbuf, 4 blk/CU --
// R12: the R11 occupancy experiment with the register spill FIXED. 4 waves
// (2x2), per-wave C = 64x64 -> acc[4][4] i32x4 = 64 regs; total ~115 <= 128
// cap at 16 waves/CU (launch_bounds(256,4); m69: 16 waves/CU at 128 regs).
// R11's 256^2 tile needed 228 regs -> launch_bounds(512,4) capped at 64 ->
// acc spilled to scratch (WRITE_SIZE 753 MB, gram 287us). Geometry is the
// ONLY change vs R8; all address math is the R7/R8-verified 8KB-half form.
// 4 independent blocks per CU drift freely -> one block's LDS-read burst
// overlaps another's MFMA burst (m114), which a single barrier-locked block
// cannot do (R8's 1.65x serial tax).
// LDS: 2 slots x {A,B} x [128 rows][64 B] = 32 KiB/block, 4 blocks = 128 KiB.
// Per iter k: stage kt k+1 (4 gll16/thread... 2 per matrix) -> 8 ds_read_b128
// -> 16 MFMA -> vmcnt(0) -> ONE barrier. No setprio (m190).
// Swizzle (R7/R8-verified, 0 conflicts): LDS byte y of an 8-KB buf holds
// global byte S(y) = y ^ (((y>>7)&7)<<4); read of (row, col=lk*16):
// (row*64 + lk*16) ^ (((lr>>1)&7)<<4) (row>>1&7 == lr>>1&7: wr*64, m*16
// vanish mod 16).
__global__ __launch_bounds__(256, 4) void grami8_kernel(
    const char* __restrict__ fq, const char* __restrict__ gq,
    int* __restrict__ rowmaxI) {
  __shared__ __align__(16) char lds[2][2][8192];  // [slot][A,B][128*64]

  // XCD swizzle: 4096 wgs, 512 contiguous per XCD (bijective, 4096%8==0).
  // Per pair: 64 tiles consecutive -> 1.5 MB working set, L2-resident.
  const int bid = blockIdx.x;
  const int wg = (bid & 7) * 512 + (bid >> 3);
  const int pair = wg >> 6;                 // 0..63
  const int tile = wg & 63;
  const int fn = pair >> 3, gm = pair & 7;
  const int mt = tile >> 3, nt = tile & 7;  // 8x8 tiles of 128x128
  const int brow = mt * 128, bcol = nt * 128;

  const int t = threadIdx.x;
  const int lane = t & 63, wave = t >> 6;
  const int lr = lane & 15, lk = lane >> 4;
  const int wr = wave >> 1, wc = wave & 1;  // 2x2 waves, per-wave 64x64

  const char* rowA = fq + ((size_t)fn * PP + brow) * DD;
  const char* rowB = gq + ((size_t)gm * PP + bcol) * DD;

  // Staging source mapping (R7/R8-verified, 8-KB buf = 512 chunks; thread t
  // handles chunks c = t and t+256 per matrix):
  // x = c*16 ^ (((c>>3)&7)<<4); srow = x>>6 (0..127); scol = x&63.
  int srow[2], scol[2];
#pragma unroll
  for (int j = 0; j < 2; ++j) {
    const int c = t + j * 256;
    const int x = (c * 16) ^ (((c >> 3) & 7) << 4);
    srow[j] = x >> 6;
    scol[j] = x & 63;
  }

  // Fragment read byte offsets within an 8-KB buf (R7/R8-verified form).
  const int swzv = ((lr >> 1) & 7) << 4;
  const int abase = ((wr * 64 + lr) * 64 + lk * 16) ^ swzv;  // + m*1024
  const int bbase = ((wc * 64 + lr) * 64 + lk * 16) ^ swzv;  // + n*1024

#define STAGE(rowPtr, kt, slot, mat)                                      \
  do {                                                                    \
    _Pragma("unroll")                                                     \
    for (int j = 0; j < 2; ++j)                                           \
      gll16(rowPtr + (size_t)srow[j] * DD + (kt) * 64 + scol[j],          \
            &lds[slot][mat][(t + j * 256) * 16]);                         \
  } while (0)

  i32x4 acc[4][4];
#pragma unroll
  for (int i = 0; i < 4; ++i)
#pragma unroll
    for (int j = 0; j < 4; ++j) acc[i][j] = (i32x4){0, 0, 0, 0};

  // Prologue: stage kt 0 into slot 0.
  STAGE(rowB, 0, 0, 1);
  STAGE(rowA, 0, 0, 0);
  asm volatile("s_waitcnt vmcnt(0)" ::: "memory");
  __builtin_amdgcn_s_barrier();
  asm volatile("" ::: "memory");

#pragma unroll 1
  for (int k = 0; k < NKT; ++k) {
    const char* Ab = &lds[k & 1][0][0];
    const char* Bb = &lds[k & 1][1][0];

    // Stage kt k+1 into the other slot (readers of that slot drained before
    // the iter-(k-1) closing barrier; writes land under this iter's MFMA).
    if (k + 1 < NKT) {
      const int ns = (k + 1) & 1;
      STAGE(rowB, k + 1, ns, 1);
      STAGE(rowA, k + 1, ns, 0);
    }

    // 8 ds_read_b128; compiler-graduated lgkmcnt before dependent MFMAs.
    i32x4 a[4], b[4];
#pragma unroll
    for (int n = 0; n < 4; ++n)
      b[n] = *(const i32x4*)(Bb + bbase + n * 1024);
#pragma unroll
    for (int m = 0; m < 4; ++m)
      a[m] = *(const i32x4*)(Ab + abase + m * 1024);

#pragma unroll
    for (int m = 0; m < 4; ++m)
#pragma unroll
      for (int n = 0; n < 4; ++n)
        acc[m][n] = __builtin_amdgcn_mfma_i32_16x16x64_i8(a[m], b[n],
                                                          acc[m][n], 0, 0, 0);

    // Slot k+1 must be resident before next iter's reads.
    asm volatile("s_waitcnt vmcnt(0)" ::: "memory");
    __builtin_amdgcn_s_barrier();
    asm volatile("" ::: "memory");
  }

  // Row-max epilogue (i32 dot monotone with gram). C/D layout: col = lr,
  // row = lk*4 + reg.
  int* rm = rowmaxI + (size_t)(fn * 8 + gm) * PP;
#pragma unroll
  for (int m = 0; m < 4; ++m) {
#pragma unroll
    for (int r = 0; r < 4; ++r) {
      int vv = max(max(acc[m][0][r], acc[m][1][r]),
                   max(acc[m][2][r], acc[m][3][r]));
      vv = max(vv, __shfl_xor(vv, 1, 64));
      vv = max(vv, __shfl_xor(vv, 2, 64));
      vv = max(vv, __shfl_xor(vv, 4, 64));
      vv = max(vv, __shfl_xor(vv, 8, 64));
      if (lr == 0) {
        const int row = brow + wr * 64 + m * 16 + lk * 4 + r;
        atomicMax(&rm[row], vv);
      }
    }
  }
#undef STAGE
}

// ---------------- K3: rowmax(i32) -> dist -> scores + sp ----------------
__global__ __launch_bounds__(256) void finalize_kernel(
    const int* __restrict__ rowmaxI, float* __restrict__ sp,
    float* __restrict__ scores) {
  const int n = blockIdx.x, t = threadIdx.x;
  const int lane = t & 63, wave = t >> 6;
  __shared__ float red[4];
  __shared__ float maxd[N2];
  float spacc[4] = {0.f, 0.f, 0.f, 0.f};
  for (int m = 0; m < N2; ++m) {
    float lmax = -1e30f;
#pragma unroll
    for (int i = 0; i < 4; ++i) {
      const int p = t + i * 256;
      const float g = (float)rowmaxI[(size_t)(n * N2 + m) * PP + p] *
                      (1.0f / 16129.0f);  // 127^2
      const float d = 0.5f * sqrtf(fmaxf(0.f, 2.f - 2.f * g));
      spacc[i] += d;
      lmax = fmaxf(lmax, d);
    }
#pragma unroll
    for (int msk = 32; msk; msk >>= 1) lmax = fmaxf(lmax, __shfl_xor(lmax, msk, 64));
    if (lane == 0) red[wave] = lmax;
    __syncthreads();
    if (t == 0) maxd[m] = fmaxf(fmaxf(red[0], red[1]), fmaxf(red[2], red[3]));
    __syncthreads();
  }
  if (t == 0) {
    float s = 0.f;
    for (int m = 0; m < N2; ++m) s += maxd[m];
    scores[n] = s * (1.0f / N2);
  }
#pragma unroll
  for (int i = 0; i < 4; ++i)
    sp[(size_t)n * PP + t + i * 256] = spacc[i] * (1.0f / N2);
}

// ---------------- K4: bilinear resize 32x32 -> 512x512 ----------------
__global__ __launch_bounds__(256) void resize_kernel(
    const float* __restrict__ sp, float* __restrict__ out) {
  const int idx = blockIdx.x * 256 + threadIdx.x;
  const int ox = idx & (OW - 1);
  const int oy = (idx >> 9) & (OH - 1);
  const int n = idx >> 18;
  const float sy = (oy + 0.5f) * ((float)PH / OH) - 0.5f;
  const float sx = (ox + 0.5f) * ((float)PW / OW) - 0.5f;
  const float y0f = floorf(sy), x0f = floorf(sx);
  const float wy = sy - y0f, wx = sx - x0f;
  int y0 = (int)y0f, x0 = (int)x0f;
  int y1 = y0 + 1, x1 = x0 + 1;
  y0 = min(max(y0, 0), PH - 1);
  y1 = min(max(y1, 0), PH - 1);
  x0 = min(max(x0, 0), PW - 1);
  x1 = min(max(x1, 0), PW - 1);
  const float* s = sp + (size_t)n * PP;
  const float v00 = s[y0 * PW + x0], v01 = s[y0 * PW + x1];
  const float v10 = s[y1 * PW + x0], v11 = s[y1 * PW + x1];
  const float top = v00 * (1.f - wx) + v01 * wx;
  const float bot = v10 * (1.f - wx) + v11 * wx;
  out[idx] = top * (1.f - wy) + bot * wy;
}

extern "C" void kernel_launch(void* const* d_in, const int* in_sizes, int n_in,
                              void* d_out, int out_size, void* d_ws, size_t ws_size,
                              hipStream_t stream) {
  const float* feats = (const float*)d_in[0];
  const float* nfeats = (const float*)d_in[1];
  float* out = (float*)d_out;

  char* ws = (char*)d_ws;
  const size_t FQ_BYTES = (size_t)N1 * PP * DD;  // 6,291,456
  char* fq = ws;
  char* gq = ws + FQ_BYTES;
  int* rowmaxI = (int*)(ws + 2 * FQ_BYTES);
  float* sp = (float*)(ws + 2 * FQ_BYTES + (size_t)N1 * N2 * PP * 4);

  // rowmax sentinel: 0x80808080 = -2139062144 < -768*127^2 (min possible dot)
  hipMemsetAsync(rowmaxI, 0x80, (size_t)N1 * N2 * PP * 4, stream);

  nrm_kernel<<<(N1 + N2) * PP, 256, 0, stream>>>(feats, nfeats, fq, gq);

  grami8_kernel<<<4096, 256, 0, stream>>>(fq, gq, rowmaxI);

  finalize_kernel<<<N1, 256, 0, stream>>>(rowmaxI, sp, out);
  resize_kernel<<<(N1 * OH * OW) / 256, 256, 0, stream>>>(sp, out + 8);
}